// Round 6
// baseline (450.740 us; speedup 1.0000x reference)
//
#include <hip/hip_runtime.h>
#include <hip/hip_bf16.h>

#define NROWS 16384
#define DBK   768
#define DDIM  256
#define NC    201
#define NK    5
#define NCK   1005

// output offsets (floats)
#define O_PPL    12864
#define O_IMG    16478784
#define O_CONTR  16543104
#define O_TGT    33009024
#define O_NEWP   33025408

// workspace offsets (floats)
#define W_PATCH  0u
#define W_PROTON 4194304u
#define W_CORR   4451584u

__device__ __forceinline__ float waveRedSum(float v){
  #pragma unroll
  for(int o=32;o>0;o>>=1) v += __shfl_xor(v,o,64);
  return v;
}

// ---------------- GEMM1: patches_raw = patch_tokens @ proj_w^T + bias ----------------
__global__ __launch_bounds__(256,4) void k_gemm1(
    const float* __restrict__ A, const float* __restrict__ W,
    const float* __restrict__ bias, float* __restrict__ out)
{
  __shared__ __align__(16) float As[32][68];
  __shared__ __align__(16) float Bs[32][68];
  const int tid = threadIdx.x;
  const int m0 = blockIdx.x * 64;
  const int n0 = blockIdx.y * 64;
  const int tm = (tid >> 4) << 2;
  const int tn = (tid & 15) << 2;
  const int lr = tid >> 3;
  const int lc = (tid & 7) << 2;
  float acc[4][4] = {{0.f}};
  const float* Ap = A + (size_t)(m0+lr)*DBK + lc;
  const float* Wp = W + (size_t)(n0+lr)*DBK + lc;
  for (int k0 = 0; k0 < DBK; k0 += 32) {
    float4 a0 = *(const float4*)(Ap + k0);
    float4 a1 = *(const float4*)(Ap + 32*DBK + k0);
    float4 b0 = *(const float4*)(Wp + k0);
    float4 b1 = *(const float4*)(Wp + 32*DBK + k0);
    __syncthreads();
    As[lc+0][lr]=a0.x; As[lc+1][lr]=a0.y; As[lc+2][lr]=a0.z; As[lc+3][lr]=a0.w;
    As[lc+0][lr+32]=a1.x; As[lc+1][lr+32]=a1.y; As[lc+2][lr+32]=a1.z; As[lc+3][lr+32]=a1.w;
    Bs[lc+0][lr]=b0.x; Bs[lc+1][lr]=b0.y; Bs[lc+2][lr]=b0.z; Bs[lc+3][lr]=b0.w;
    Bs[lc+0][lr+32]=b1.x; Bs[lc+1][lr+32]=b1.y; Bs[lc+2][lr+32]=b1.z; Bs[lc+3][lr+32]=b1.w;
    __syncthreads();
    #pragma unroll
    for (int kk=0;kk<32;kk++){
      const float4 av = *(const float4*)&As[kk][tm];
      const float4 bv = *(const float4*)&Bs[kk][tn];
      float ar[4]={av.x,av.y,av.z,av.w};
      float br[4]={bv.x,bv.y,bv.z,bv.w};
      #pragma unroll
      for(int i=0;i<4;i++)
        #pragma unroll
        for(int j=0;j<4;j++)
          acc[i][j] = fmaf(ar[i], br[j], acc[i][j]);
    }
  }
  float4 bb = *(const float4*)&bias[n0+tn];
  float bbr[4]={bb.x,bb.y,bb.z,bb.w};
  #pragma unroll
  for(int i=0;i<4;i++){
    float4 o;
    o.x=acc[i][0]+bbr[0]; o.y=acc[i][1]+bbr[1];
    o.z=acc[i][2]+bbr[2]; o.w=acc[i][3]+bbr[3];
    *(float4*)&out[(size_t)(m0+tm+i)*DDIM + (n0+tn)] = o;
  }
}

// ---------------- LayerNorm + L2-normalize (in place, wave per row) ----------------
__global__ __launch_bounds__(256) void k_ln(float* __restrict__ p,
    const float* __restrict__ g, const float* __restrict__ bta)
{
  const int wid = threadIdx.x >> 6, lane = threadIdx.x & 63;
  const int row = blockIdx.x * 4 + wid;
  float4 x = *(float4*)&p[(size_t)row*DDIM + lane*4];
  float s = x.x + x.y + x.z + x.w;
  s = waveRedSum(s);
  const float mu = s * (1.f/256.f);
  const float d0=x.x-mu, d1=x.y-mu, d2=x.z-mu, d3=x.w-mu;
  float ss = d0*d0 + d1*d1 + d2*d2 + d3*d3;
  ss = waveRedSum(ss);
  const float var = ss * (1.f/256.f);
  const float rs = rsqrtf(var + 1e-5f);
  const float4 gv = *(const float4*)&g[lane*4];
  const float4 bv = *(const float4*)&bta[lane*4];
  const float y0 = d0*rs*gv.x + bv.x;
  const float y1 = d1*rs*gv.y + bv.y;
  const float y2 = d2*rs*gv.z + bv.z;
  const float y3 = d3*rs*gv.w + bv.w;
  float n2 = y0*y0 + y1*y1 + y2*y2 + y3*y3;
  n2 = waveRedSum(n2);
  const float inv = 1.f / fmaxf(sqrtf(n2), 1e-12f);
  float4 o; o.x=y0*inv; o.y=y1*inv; o.z=y2*inv; o.w=y3*inv;
  *(float4*)&p[(size_t)row*DDIM + lane*4] = o;
}

// ---------------- prototype L2-normalize (wave per row) ----------------
__global__ __launch_bounds__(256) void k_pnorm(const float* __restrict__ pr, float* __restrict__ out)
{
  const int wid = threadIdx.x >> 6, lane = threadIdx.x & 63;
  const int row = blockIdx.x * 4 + wid;
  if (row >= NCK) return;
  const float4 x = *(const float4*)&pr[(size_t)row*DDIM + lane*4];
  float n2 = x.x*x.x + x.y*x.y + x.z*x.z + x.w*x.w;
  n2 = waveRedSum(n2);
  const float inv = 1.f / fmaxf(sqrtf(n2), 1e-12f);
  float4 o; o.x=x.x*inv; o.y=x.y*inv; o.z=x.z*inv; o.w=x.w*inv;
  *(float4*)&out[(size_t)row*DDIM + lane*4] = o;
}

// ---------------- GEMM2: logits = patches @ protos_n^T, dual-layout store ----------------
__global__ __launch_bounds__(256,4) void k_gemm2(
    const float* __restrict__ A, const float* __restrict__ P,
    float* __restrict__ ct, float* __restrict__ ppl)
{
  __shared__ __align__(16) float As[32][68];
  __shared__ __align__(16) float Bs[32][68];
  const int tid = threadIdx.x;
  const int m0 = blockIdx.x * 64;
  const int n0 = blockIdx.y * 64;
  const int tm = (tid >> 4) << 2;
  const int tn = (tid & 15) << 2;
  const int lr = tid >> 3;
  const int lc = (tid & 7) << 2;
  float acc[4][4] = {{0.f}};
  const int r0 = n0 + lr, r1 = n0 + lr + 32;
  const float* Ap = A + (size_t)(m0+lr)*DDIM + lc;
  for (int k0 = 0; k0 < DDIM; k0 += 32) {
    float4 a0 = *(const float4*)(Ap + k0);
    float4 a1 = *(const float4*)(Ap + 32*DDIM + k0);
    float4 b0 = make_float4(0.f,0.f,0.f,0.f);
    float4 b1 = make_float4(0.f,0.f,0.f,0.f);
    if (r0 < NCK) b0 = *(const float4*)&P[(size_t)r0*DDIM + k0 + lc];
    if (r1 < NCK) b1 = *(const float4*)&P[(size_t)r1*DDIM + k0 + lc];
    __syncthreads();
    As[lc+0][lr]=a0.x; As[lc+1][lr]=a0.y; As[lc+2][lr]=a0.z; As[lc+3][lr]=a0.w;
    As[lc+0][lr+32]=a1.x; As[lc+1][lr+32]=a1.y; As[lc+2][lr+32]=a1.z; As[lc+3][lr+32]=a1.w;
    Bs[lc+0][lr]=b0.x; Bs[lc+1][lr]=b0.y; Bs[lc+2][lr]=b0.z; Bs[lc+3][lr]=b0.w;
    Bs[lc+0][lr+32]=b1.x; Bs[lc+1][lr+32]=b1.y; Bs[lc+2][lr+32]=b1.z; Bs[lc+3][lr+32]=b1.w;
    __syncthreads();
    #pragma unroll
    for (int kk=0;kk<32;kk++){
      const float4 av = *(const float4*)&As[kk][tm];
      const float4 bv = *(const float4*)&Bs[kk][tn];
      float ar[4]={av.x,av.y,av.z,av.w};
      float br[4]={bv.x,bv.y,bv.z,bv.w};
      #pragma unroll
      for(int i=0;i<4;i++)
        #pragma unroll
        for(int j=0;j<4;j++)
          acc[i][j] = fmaf(ar[i], br[j], acc[i][j]);
    }
  }
  const int bimg = m0 >> 8;
  const int hw0 = (m0 & 255) + tm;
  // contrast_logits [n][ck] (scalar stores: row stride 1005 breaks 16B alignment)
  #pragma unroll
  for(int i=0;i<4;i++){
    const size_t base = (size_t)(m0+tm+i)*NCK + (n0+tn);
    #pragma unroll
    for(int j=0;j<4;j++){
      if (n0+tn+j < NCK) ct[base+j] = acc[i][j];
    }
  }
  // ppl [b][ck][hw] (aligned float4 down the row dimension)
  #pragma unroll
  for(int j=0;j<4;j++){
    const int ck = n0+tn+j;
    if (ck < NCK){
      float4 o; o.x=acc[0][j]; o.y=acc[1][j]; o.z=acc[2][j]; o.w=acc[3][j];
      *(float4*)&ppl[((size_t)(bimg*NCK+ck))*256 + hw0] = o;
    }
  }
}

// ---------------- img_logits: mean over hw per (b,ck) ----------------
__global__ __launch_bounds__(256) void k_img(const float* __restrict__ ppl, float* __restrict__ img)
{
  const int b = blockIdx.x;
  const int wid = threadIdx.x >> 6, lane = threadIdx.x & 63;
  const int ck = blockIdx.y * 4 + wid;
  if (ck >= NCK) return;
  const float* rp = &ppl[((size_t)(b*NCK+ck))*256];
  const float4 v = *(const float4*)&rp[lane*4];
  float s = v.x + v.y + v.z + v.w;
  s = waveRedSum(s);
  if (lane == 0) img[(size_t)b*NCK + ck] = s * (1.f/256.f);
}

// ---------------- pred_logits: sum over k ----------------
__global__ __launch_bounds__(256) void k_pred(const float* __restrict__ img, float* __restrict__ pred)
{
  const int gid = blockIdx.x*256 + threadIdx.x;
  if (gid >= 64*NC) return;
  const int b = gid / NC, c = gid % NC;
  const float* ip = &img[(size_t)b*NCK + c*5];
  pred[(size_t)b*NC + c] = ip[0]+ip[1]+ip[2]+ip[3]+ip[4];
}

// ---------------- class_preds -> correct_f (wave per row) ----------------
__global__ __launch_bounds__(256) void k_cls(const float* __restrict__ ct,
    const int* __restrict__ mask, float* __restrict__ corr)
{
  const int wid = threadIdx.x >> 6, lane = threadIdx.x & 63;
  const int n = blockIdx.x * 4 + wid;
  const float* row = &ct[(size_t)n*NCK];
  float bv = -1e30f; int bc = 0x7FFFFFFF;
  #pragma unroll
  for(int j=0;j<16;j++){
    const int ck = lane + 64*j;
    if (ck < NCK){
      const float v = row[ck];
      const int c = ck / 5;
      if (v > bv || (v == bv && c < bc)){ bv = v; bc = c; }
    }
  }
  #pragma unroll
  for(int o=32;o>0;o>>=1){
    const float ov = __shfl_xor(bv,o,64);
    const int   oc = __shfl_xor(bc,o,64);
    if (ov > bv || (ov == bv && oc < bc)){ bv = ov; bc = oc; }
  }
  if (lane == 0) corr[n] = (mask[n] == bc) ? 1.f : 0.f;
}

// ---------------- per-class Sinkhorn + prototype update ----------------
__device__ __forceinline__ void blockRed6(float* a, float* sred){
  #pragma unroll
  for(int j=0;j<6;j++) a[j] = waveRedSum(a[j]);
  const int wv = threadIdx.x >> 6, lane = threadIdx.x & 63;
  __syncthreads();
  if (lane == 0){
    #pragma unroll
    for(int j=0;j<6;j++) sred[wv*6+j] = a[j];
  }
  __syncthreads();
  #pragma unroll
  for(int j=0;j<6;j++){
    float s = 0.f;
    #pragma unroll
    for(int w2=0;w2<8;w2++) s += sred[w2*6+j];
    a[j] = s;
  }
}

__device__ __forceinline__ float blockSum512(float x, float* s8){
  x = waveRedSum(x);
  const int wv = threadIdx.x >> 6, lane = threadIdx.x & 63;
  __syncthreads();
  if (lane == 0) s8[wv] = x;
  __syncthreads();
  float s = 0.f;
  #pragma unroll
  for(int w2=0;w2<8;w2++) s += s8[w2];
  return s;
}

__global__ __launch_bounds__(512,2) void k_sinkhorn(
    const float* __restrict__ ppl, const int* __restrict__ mask,
    const float* __restrict__ corr, const float* __restrict__ patches,
    const float* __restrict__ pnorm, float* __restrict__ tgt, float* __restrict__ newp)
{
  const int c  = blockIdx.x;
  const int c5 = c * 5;
  const int tid = threadIdx.x;
  __shared__ float sred[48];
  __shared__ float srv[40];
  __shared__ int   srn[40];

#define LGPTR(n) (ppl + ((size_t)(((n)>>8)*NCK) + c5)*256 + ((n)&255))

  // pass 0: masked column sums of E = exp(logit/eps), mask bits, Bc
  unsigned mb = 0;
  float cs[6] = {0.f,0.f,0.f,0.f,0.f,0.f};
  #pragma unroll
  for(int i=0;i<32;i++){
    const int n = tid + 512*i;
    if (mask[n] == c){
      mb |= (1u << i);
      cs[5] += 1.f;
      const float* lp = LGPTR(n);
      cs[0] += expf(lp[0]   *20.f);
      cs[1] += expf(lp[256] *20.f);
      cs[2] += expf(lp[512] *20.f);
      cs[3] += expf(lp[768] *20.f);
      cs[4] += expf(lp[1024]*20.f);
    }
  }
  blockRed6(cs, sred);
  const float Bc  = cs[5];
  const float Bcc = fmaxf(Bc, 1.f);
  const float S   = cs[0]+cs[1]+cs[2]+cs[3]+cs[4];
  const float v0  = 1.f / fmaxf(S, 1e-12f);
  float v[5];
  #pragma unroll
  for(int k=0;k<5;k++) v[k] = v0 / (fmaxf(v0*cs[k], 1e-12f) * 5.f);

  // fused (row-step of iter t) + (col-accum of iter t+1), t = 1,2
  float u[32];
  #pragma unroll
  for(int i=0;i<32;i++) u[i] = 1.f;
  #pragma unroll 1
  for(int t=0;t<2;t++){
    float w5[6] = {0.f,0.f,0.f,0.f,0.f,0.f};
    #pragma unroll
    for(int i=0;i<32;i++){
      if (mb & (1u << i)){
        const int n = tid + 512*i;
        const float* lp = LGPTR(n);
        const float e0 = expf(lp[0]   *20.f);
        const float e1 = expf(lp[256] *20.f);
        const float e2 = expf(lp[512] *20.f);
        const float e3 = expf(lp[768] *20.f);
        const float e4 = expf(lp[1024]*20.f);
        const float s = e0*v[0] + e1*v[1] + e2*v[2] + e3*v[3] + e4*v[4];
        const float un = u[i] / fmaxf(u[i]*s, 1e-12f) / Bcc;
        u[i] = un;
        w5[0] += un*e0; w5[1] += un*e1; w5[2] += un*e2; w5[3] += un*e3; w5[4] += un*e4;
      }
    }
    blockRed6(w5, sred);
    #pragma unroll
    for(int k=0;k<5;k++) v[k] = v[k] / (fmaxf(v[k]*w5[k], 1e-12f) * 5.f);
  }

  // final pass: per-row argmax (idx), contrast_target, score candidates
  float bv5[5]; int bn5[5];
  #pragma unroll
  for(int k=0;k<5;k++){ bv5[k] = -1e30f; bn5[k] = 0x7FFFFFFF; }
  #pragma unroll
  for(int i=0;i<32;i++){
    const int n = tid + 512*i;
    float val[5] = {0.f,0.f,0.f,0.f,0.f};
    if (mb & (1u << i)){
      const float* lp = LGPTR(n);
      float lg[5];
      lg[0]=lp[0]; lg[1]=lp[256]; lg[2]=lp[512]; lg[3]=lp[768]; lg[4]=lp[1024];
      const float p0 = expf(lg[0]*20.f)*v[0];
      const float p1 = expf(lg[1]*20.f)*v[1];
      const float p2 = expf(lg[2]*20.f)*v[2];
      const float p3 = expf(lg[3]*20.f)*v[3];
      const float p4 = expf(lg[4]*20.f)*v[4];
      int bi = 0; float bb = p0;
      if (p1 > bb){ bb=p1; bi=1; }
      if (p2 > bb){ bb=p2; bi=2; }
      if (p3 > bb){ bb=p3; bi=3; }
      if (p4 > bb){ bb=p4; bi=4; }
      tgt[n] = (float)(bi + c5);
      const bool cc = (corr[n] > 0.5f);
      #pragma unroll
      for(int k=0;k<5;k++) val[k] = (cc && bi == k) ? lg[k] : 0.f;
    }
    #pragma unroll
    for(int k=0;k<5;k++){
      if (val[k] > bv5[k] || (val[k] == bv5[k] && n < bn5[k])){ bv5[k]=val[k]; bn5[k]=n; }
    }
  }
  #pragma unroll
  for(int k=0;k<5;k++){
    #pragma unroll
    for(int o=32;o>0;o>>=1){
      const float ov = __shfl_xor(bv5[k],o,64);
      const int   on = __shfl_xor(bn5[k],o,64);
      if (ov > bv5[k] || (ov == bv5[k] && on < bn5[k])){ bv5[k]=ov; bn5[k]=on; }
    }
  }
  const int wv = tid >> 6, lane = tid & 63;
  __syncthreads();
  if (lane == 0){
    #pragma unroll
    for(int k=0;k<5;k++){ srv[wv*5+k]=bv5[k]; srn[wv*5+k]=bn5[k]; }
  }
  __syncthreads();
  int topn[5];
  #pragma unroll
  for(int k=0;k<5;k++){
    float bb = srv[k]; int nn = srn[k];
    #pragma unroll
    for(int w2=1;w2<8;w2++){
      const float ov = srv[w2*5+k]; const int on = srn[w2*5+k];
      if (ov > bb || (ov == bb && on < nn)){ bb=ov; nn=on; }
    }
    topn[k] = nn;
  }
  __syncthreads();

  // prototype update: P_new = l2n(patches_correct[topn]); EMA; l2n
  const bool hasp = (Bc > 0.f);
  #pragma unroll
  for(int k=0;k<5;k++){
    const int tn_ = topn[k];
    const float cf = corr[tn_];
    float pv = 0.f, proto = 0.f;
    if (tid < 256){
      pv    = patches[(size_t)tn_*DDIM + tid] * cf;
      proto = pnorm[(size_t)(c5+k)*DDIM + tid];
    }
    const float ss = blockSum512(pv*pv, sred);
    const float pnv = pv / fmaxf(sqrtf(ss), 1e-12f);
    const float pu = hasp ? (0.999f*proto + 0.001f*pnv) : proto;
    const float ss2 = blockSum512(tid<256 ? pu*pu : 0.f, sred);
    if (tid < 256) newp[(size_t)(c5+k)*DDIM + tid] = pu / fmaxf(sqrtf(ss2), 1e-12f);
  }
#undef LGPTR
}

extern "C" void kernel_launch(void* const* d_in, const int* in_sizes, int n_in,
                              void* d_out, int out_size, void* d_ws, size_t ws_size,
                              hipStream_t stream)
{
  const float* patch_tokens = (const float*)d_in[0];
  const float* proj_w       = (const float*)d_in[1];
  const float* proj_b       = (const float*)d_in[2];
  const float* ln_g         = (const float*)d_in[3];
  const float* ln_b         = (const float*)d_in[4];
  const float* prototypes   = (const float*)d_in[5];
  const int*   mask         = (const int*)d_in[6];
  float* out = (float*)d_out;
  float* ws  = (float*)d_ws;

  float* patches = ws + W_PATCH;
  float* pn      = ws + W_PROTON;
  float* corr    = ws + W_CORR;

  float* pred = out;
  float* ppl  = out + O_PPL;
  float* img  = out + O_IMG;
  float* ct   = out + O_CONTR;
  float* tgt  = out + O_TGT;
  float* newp = out + O_NEWP;

  k_gemm1<<<dim3(256,4),256,0,stream>>>(patch_tokens, proj_w, proj_b, patches);
  k_ln<<<4096,256,0,stream>>>(patches, ln_g, ln_b);
  k_pnorm<<<252,256,0,stream>>>(prototypes, pn);
  k_gemm2<<<dim3(256,16),256,0,stream>>>(patches, pn, ct, ppl);
  k_img<<<dim3(64,252),256,0,stream>>>(ppl, img);
  k_pred<<<51,256,0,stream>>>(img, pred);
  k_cls<<<4096,256,0,stream>>>(ct, mask, corr);
  k_sinkhorn<<<201,512,0,stream>>>(ppl, mask, corr, patches, pn, tgt, newp);
}

// Round 9
// 376.446 us; speedup vs baseline: 1.1974x; 1.1974x over previous
//
#include <hip/hip_runtime.h>
#include <hip/hip_bf16.h>

#define NROWS 16384
#define DBK   768
#define DDIM  256
#define NC    201
#define NK    5
#define NCK   1005

// output offsets (floats)
#define O_PPL    12864
#define O_IMG    16478784
#define O_CONTR  16543104
#define O_TGT    33009024
#define O_NEWP   33025408

// workspace offsets (floats)
#define W_PATCH  0u
#define W_PN     4194304u
#define W_CORR   4451584u
#define W_MEANP  4467968u
#define W_PBF    4484352u   // ushort region: 16384*256 bf16 patches
#define W_PNBF   8678656u   // ushort region: 1024*256 bf16 protos (zero-padded)

typedef __attribute__((ext_vector_type(8))) short     short8;   // 8 bf16
typedef __attribute__((ext_vector_type(4))) float     f32x4;
typedef __attribute__((ext_vector_type(4))) unsigned int uint4v;
typedef __attribute__((ext_vector_type(4))) unsigned short ushort4v;

__device__ __forceinline__ float waveRedSum(float v){
  #pragma unroll
  for(int o=32;o>0;o>>=1) v += __shfl_xor(v,o,64);
  return v;
}

__device__ __forceinline__ unsigned short f2bf(float x){
  union { float f; unsigned u; } c; c.f = x;
  unsigned r = c.u + 0x7FFFu + ((c.u >> 16) & 1u);  // RNE
  return (unsigned short)(r >> 16);
}
__device__ __forceinline__ unsigned pack2(float a, float b){
  return (unsigned)f2bf(a) | ((unsigned)f2bf(b) << 16);
}
__device__ __forceinline__ uint4v pack8(float4 lo, float4 hi){
  uint4v u;
  u[0] = pack2(lo.x, lo.y); u[1] = pack2(lo.z, lo.w);
  u[2] = pack2(hi.x, hi.y); u[3] = pack2(hi.z, hi.w);
  return u;
}

// ============ GEMM1 (MFMA): out = patch_tokens @ proj_w^T + bias (fp32 in, fp32 out) ============
// 128x128 tile, 4 waves (2x2 of 64x64), BK=32, fp32->bf16 cvt during staging.
// LDS swizzle: 16B-slot ^= (row>>1)&3  -> conflict-free b128 read/write.
__global__ __launch_bounds__(256,2) void k_gemm1m(
    const float* __restrict__ A, const float* __restrict__ W,
    const float* __restrict__ bias, float* __restrict__ out)
{
  __shared__ ushort As[4096];
  __shared__ ushort Bs[4096];
  const int tid = threadIdx.x;
  const int m0 = blockIdx.x * 128;
  const int n0 = blockIdx.y * 128;
  const int lane = tid & 63, wid = tid >> 6;
  const int wr = wid >> 1, wc = wid & 1;
  const int srow = tid >> 2, sslot = tid & 3;
  const int woff  = srow*32      + (sslot ^ ((srow>>1)&3))*8;  // rows 0..63
  const int woff2 = (srow+64)*32 + (sslot ^ ((srow>>1)&3))*8;  // rows 64..127 (same swz bits)
  const int l15 = lane & 15, kg = lane >> 4;
  const int rslot = (kg ^ ((l15>>1)&3))*8;
  f32x4 acc[4][4] = {};
  const float* Ap0 = A + (size_t)(m0+srow)*DBK + sslot*8;
  const float* Ap1 = Ap0 + (size_t)64*DBK;
  const float* Wp0 = W + (size_t)(n0+srow)*DBK + sslot*8;
  const float* Wp1 = Wp0 + (size_t)64*DBK;
  for (int k0 = 0; k0 < DBK; k0 += 32) {
    float4 a00 = *(const float4*)(Ap0+k0), a01 = *(const float4*)(Ap0+k0+4);
    float4 a10 = *(const float4*)(Ap1+k0), a11 = *(const float4*)(Ap1+k0+4);
    float4 b00 = *(const float4*)(Wp0+k0), b01 = *(const float4*)(Wp0+k0+4);
    float4 b10 = *(const float4*)(Wp1+k0), b11 = *(const float4*)(Wp1+k0+4);
    __syncthreads();
    *(uint4v*)&As[woff]  = pack8(a00, a01);
    *(uint4v*)&As[woff2] = pack8(a10, a11);
    *(uint4v*)&Bs[woff]  = pack8(b00, b01);
    *(uint4v*)&Bs[woff2] = pack8(b10, b11);
    __syncthreads();
    short8 af[4], bf[4];
    #pragma unroll
    for (int i=0;i<4;i++){
      af[i] = *(const short8*)&As[(wr*64 + i*16 + l15)*32 + rslot];
      bf[i] = *(const short8*)&Bs[(wc*64 + i*16 + l15)*32 + rslot];
    }
    #pragma unroll
    for (int i=0;i<4;i++)
      #pragma unroll
      for (int j=0;j<4;j++)
        acc[i][j] = __builtin_amdgcn_mfma_f32_16x16x32_bf16(af[i], bf[j], acc[i][j], 0,0,0);
  }
  #pragma unroll
  for (int j=0;j<4;j++){
    const int ncol = n0 + wc*64 + j*16 + l15;
    const float bv = bias[ncol];
    #pragma unroll
    for (int i=0;i<4;i++){
      const int mrow = m0 + wr*64 + i*16 + kg*4;
      #pragma unroll
      for (int r=0;r<4;r++)
        out[(size_t)(mrow+r)*DDIM + ncol] = acc[i][j][r] + bv;
    }
  }
}

// ============ GEMM2 (MFMA): logits = patches_bf16 @ pn_bf16^T, dual-layout fp32 store ============
__global__ __launch_bounds__(256,2) void k_gemm2m(
    const ushort* __restrict__ A, const ushort* __restrict__ B,
    float* __restrict__ ct, float* __restrict__ ppl)
{
  __shared__ ushort As[4096];
  __shared__ ushort Bs[4096];
  const int tid = threadIdx.x;
  const int m0 = blockIdx.x * 128;
  const int n0 = blockIdx.y * 128;   // 8 tiles cover 1024 (B zero-padded)
  const int lane = tid & 63, wid = tid >> 6;
  const int wr = wid >> 1, wc = wid & 1;
  const int srow = tid >> 2, sslot = tid & 3;
  const int woff  = srow*32      + (sslot ^ ((srow>>1)&3))*8;
  const int woff2 = (srow+64)*32 + (sslot ^ ((srow>>1)&3))*8;
  const int l15 = lane & 15, kg = lane >> 4;
  const int rslot = (kg ^ ((l15>>1)&3))*8;
  f32x4 acc[4][4] = {};
  const ushort* Ap0 = A + (size_t)(m0+srow)*DDIM + sslot*8;
  const ushort* Ap1 = Ap0 + (size_t)64*DDIM;
  const ushort* Bp0 = B + (size_t)(n0+srow)*DDIM + sslot*8;
  const ushort* Bp1 = Bp0 + (size_t)64*DDIM;
  for (int k0 = 0; k0 < DDIM; k0 += 32) {
    uint4v a0 = *(const uint4v*)(Ap0+k0);
    uint4v a1 = *(const uint4v*)(Ap1+k0);
    uint4v b0 = *(const uint4v*)(Bp0+k0);
    uint4v b1 = *(const uint4v*)(Bp1+k0);
    __syncthreads();
    *(uint4v*)&As[woff]  = a0;
    *(uint4v*)&As[woff2] = a1;
    *(uint4v*)&Bs[woff]  = b0;
    *(uint4v*)&Bs[woff2] = b1;
    __syncthreads();
    short8 af[4], bf[4];
    #pragma unroll
    for (int i=0;i<4;i++){
      af[i] = *(const short8*)&As[(wr*64 + i*16 + l15)*32 + rslot];
      bf[i] = *(const short8*)&Bs[(wc*64 + i*16 + l15)*32 + rslot];
    }
    #pragma unroll
    for (int i=0;i<4;i++)
      #pragma unroll
      for (int j=0;j<4;j++)
        acc[i][j] = __builtin_amdgcn_mfma_f32_16x16x32_bf16(af[i], bf[j], acc[i][j], 0,0,0);
  }
  const int bimg = m0 >> 8;
  #pragma unroll
  for (int i=0;i<4;i++){
    const int mrow = m0 + wr*64 + i*16 + kg*4;   // 4 consecutive rows per lane (reg r)
    const int hw = mrow & 255;
    #pragma unroll
    for (int j=0;j<4;j++){
      const int ck = n0 + wc*64 + j*16 + l15;
      if (ck < NCK){
        #pragma unroll
        for (int r=0;r<4;r++)
          ct[(size_t)(mrow+r)*NCK + ck] = acc[i][j][r];
        *(f32x4*)&ppl[((size_t)(bimg*NCK+ck))*256 + hw] = acc[i][j];
      }
    }
  }
}

// ---------------- LayerNorm + L2n (in place) + bf16 copy ----------------
__global__ __launch_bounds__(256) void k_ln(float* __restrict__ p,
    const float* __restrict__ g, const float* __restrict__ bta, ushort* __restrict__ pbf)
{
  const int wid = threadIdx.x >> 6, lane = threadIdx.x & 63;
  const int row = blockIdx.x * 4 + wid;
  float4 x = *(float4*)&p[(size_t)row*DDIM + lane*4];
  float s = x.x + x.y + x.z + x.w;
  s = waveRedSum(s);
  const float mu = s * (1.f/256.f);
  const float d0=x.x-mu, d1=x.y-mu, d2=x.z-mu, d3=x.w-mu;
  float ss = d0*d0 + d1*d1 + d2*d2 + d3*d3;
  ss = waveRedSum(ss);
  const float var = ss * (1.f/256.f);
  const float rs = rsqrtf(var + 1e-5f);
  const float4 gv = *(const float4*)&g[lane*4];
  const float4 bv = *(const float4*)&bta[lane*4];
  const float y0 = d0*rs*gv.x + bv.x;
  const float y1 = d1*rs*gv.y + bv.y;
  const float y2 = d2*rs*gv.z + bv.z;
  const float y3 = d3*rs*gv.w + bv.w;
  float n2 = y0*y0 + y1*y1 + y2*y2 + y3*y3;
  n2 = waveRedSum(n2);
  const float inv = 1.f / fmaxf(sqrtf(n2), 1e-12f);
  float4 o; o.x=y0*inv; o.y=y1*inv; o.z=y2*inv; o.w=y3*inv;
  *(float4*)&p[(size_t)row*DDIM + lane*4] = o;
  ushort4v ob; ob[0]=f2bf(o.x); ob[1]=f2bf(o.y); ob[2]=f2bf(o.z); ob[3]=f2bf(o.w);
  *(ushort4v*)&pbf[(size_t)row*DDIM + lane*4] = ob;
}

// ---------------- prototype L2n -> fp32 + bf16 (rows 1005..1023 zeroed in bf16) ----------------
__global__ __launch_bounds__(256) void k_pnorm(const float* __restrict__ pr,
    float* __restrict__ out, ushort* __restrict__ obf)
{
  const int wid = threadIdx.x >> 6, lane = threadIdx.x & 63;
  const int row = blockIdx.x * 4 + wid;   // 0..1023
  if (row >= NCK){
    ushort4v z = {0,0,0,0};
    *(ushort4v*)&obf[(size_t)row*DDIM + lane*4] = z;
    return;
  }
  const float4 x = *(const float4*)&pr[(size_t)row*DDIM + lane*4];
  float n2 = x.x*x.x + x.y*x.y + x.z*x.z + x.w*x.w;
  n2 = waveRedSum(n2);
  const float inv = 1.f / fmaxf(sqrtf(n2), 1e-12f);
  float4 o; o.x=x.x*inv; o.y=x.y*inv; o.z=x.z*inv; o.w=x.w*inv;
  *(float4*)&out[(size_t)row*DDIM + lane*4] = o;
  ushort4v ob; ob[0]=f2bf(o.x); ob[1]=f2bf(o.y); ob[2]=f2bf(o.z); ob[3]=f2bf(o.w);
  *(ushort4v*)&obf[(size_t)row*DDIM + lane*4] = ob;
}

// ---------------- mean patch per image (fp32, exact-linear img path) ----------------
__global__ __launch_bounds__(256) void k_pmean(const float* __restrict__ p, float* __restrict__ mp)
{
  const int b = blockIdx.x, d = threadIdx.x;
  const float* base = p + (size_t)b*256*DDIM + d;
  float s = 0.f;
  #pragma unroll 8
  for (int r=0;r<256;r++) s += base[(size_t)r*DDIM];
  mp[b*DDIM + d] = s * (1.f/256.f);
}

// ---------------- img_logits = mean_patch . proto (fp32 dot-256) ----------------
__global__ __launch_bounds__(256) void k_img2(const float* __restrict__ mp,
    const float* __restrict__ pn, float* __restrict__ img)
{
  const int gid = blockIdx.x*256 + threadIdx.x;
  if (gid >= 64*NCK) return;
  const int b = gid / NCK, ck = gid - b*NCK;
  const float4* a = (const float4*)&mp[b*DDIM];
  const float4* q = (const float4*)&pn[(size_t)ck*DDIM];
  float s = 0.f;
  #pragma unroll 8
  for (int d=0; d<64; d++){
    const float4 x = a[d], y = q[d];
    s += x.x*y.x + x.y*y.y + x.z*y.z + x.w*y.w;
  }
  img[gid] = s;
}

// ---------------- pred_logits: sum over k ----------------
__global__ __launch_bounds__(256) void k_pred(const float* __restrict__ img, float* __restrict__ pred)
{
  const int gid = blockIdx.x*256 + threadIdx.x;
  if (gid >= 64*NC) return;
  const int b = gid / NC, c = gid % NC;
  const float* ip = &img[(size_t)b*NCK + c*5];
  pred[(size_t)b*NC + c] = ip[0]+ip[1]+ip[2]+ip[3]+ip[4];
}

// ---------------- class_preds -> correct_f (wave per row) ----------------
__global__ __launch_bounds__(256) void k_cls(const float* __restrict__ ct,
    const int* __restrict__ mask, float* __restrict__ corr)
{
  const int wid = threadIdx.x >> 6, lane = threadIdx.x & 63;
  const int n = blockIdx.x * 4 + wid;
  const float* row = &ct[(size_t)n*NCK];
  float bv = -1e30f; int bc = 0x7FFFFFFF;
  #pragma unroll
  for(int j=0;j<16;j++){
    const int ck = lane + 64*j;
    if (ck < NCK){
      const float v = row[ck];
      const int c = ck / 5;
      if (v > bv || (v == bv && c < bc)){ bv = v; bc = c; }
    }
  }
  #pragma unroll
  for(int o=32;o>0;o>>=1){
    const float ov = __shfl_xor(bv,o,64);
    const int   oc = __shfl_xor(bc,o,64);
    if (ov > bv || (ov == bv && oc < bc)){ bv = ov; bc = oc; }
  }
  if (lane == 0) corr[n] = (mask[n] == bc) ? 1.f : 0.f;
}

// ---------------- per-class Sinkhorn + prototype update ----------------
__device__ __forceinline__ void blockRed6(float* a, float* sred){
  #pragma unroll
  for(int j=0;j<6;j++) a[j] = waveRedSum(a[j]);
  const int wv = threadIdx.x >> 6, lane = threadIdx.x & 63;
  __syncthreads();
  if (lane == 0){
    #pragma unroll
    for(int j=0;j<6;j++) sred[wv*6+j] = a[j];
  }
  __syncthreads();
  #pragma unroll
  for(int j=0;j<6;j++){
    float s = 0.f;
    #pragma unroll
    for(int w2=0;w2<8;w2++) s += sred[w2*6+j];
    a[j] = s;
  }
}

__device__ __forceinline__ float blockSum512(float x, float* s8){
  x = waveRedSum(x);
  const int wv = threadIdx.x >> 6, lane = threadIdx.x & 63;
  __syncthreads();
  if (lane == 0) s8[wv] = x;
  __syncthreads();
  float s = 0.f;
  #pragma unroll
  for(int w2=0;w2<8;w2++) s += s8[w2];
  return s;
}

__global__ __launch_bounds__(512,2) void k_sinkhorn(
    const float* __restrict__ ppl, const int* __restrict__ mask,
    const float* __restrict__ corr, const float* __restrict__ patches,
    const float* __restrict__ pnorm, float* __restrict__ tgt, float* __restrict__ newp)
{
  const int c  = blockIdx.x;
  const int c5 = c * 5;
  const int tid = threadIdx.x;
  __shared__ float sred[48];
  __shared__ float srv[40];
  __shared__ int   srn[40];

#define LGPTR(n) (ppl + ((size_t)(((n)>>8)*NCK) + c5)*256 + ((n)&255))

  unsigned mb = 0;
  float cs[6] = {0.f,0.f,0.f,0.f,0.f,0.f};
  #pragma unroll
  for(int i=0;i<32;i++){
    const int n = tid + 512*i;
    if (mask[n] == c){
      mb |= (1u << i);
      cs[5] += 1.f;
      const float* lp = LGPTR(n);
      cs[0] += expf(lp[0]   *20.f);
      cs[1] += expf(lp[256] *20.f);
      cs[2] += expf(lp[512] *20.f);
      cs[3] += expf(lp[768] *20.f);
      cs[4] += expf(lp[1024]*20.f);
    }
  }
  blockRed6(cs, sred);
  const float Bc  = cs[5];
  const float Bcc = fmaxf(Bc, 1.f);
  const float S   = cs[0]+cs[1]+cs[2]+cs[3]+cs[4];
  const float v0  = 1.f / fmaxf(S, 1e-12f);
  float v[5];
  #pragma unroll
  for(int k=0;k<5;k++) v[k] = v0 / (fmaxf(v0*cs[k], 1e-12f) * 5.f);

  float u[32];
  #pragma unroll
  for(int i=0;i<32;i++) u[i] = 1.f;
  #pragma unroll 1
  for(int t=0;t<2;t++){
    float w5[6] = {0.f,0.f,0.f,0.f,0.f,0.f};
    #pragma unroll
    for(int i=0;i<32;i++){
      if (mb & (1u << i)){
        const int n = tid + 512*i;
        const float* lp = LGPTR(n);
        const float e0 = expf(lp[0]   *20.f);
        const float e1 = expf(lp[256] *20.f);
        const float e2 = expf(lp[512] *20.f);
        const float e3 = expf(lp[768] *20.f);
        const float e4 = expf(lp[1024]*20.f);
        const float s = e0*v[0] + e1*v[1] + e2*v[2] + e3*v[3] + e4*v[4];
        const float un = u[i] / fmaxf(u[i]*s, 1e-12f) / Bcc;
        u[i] = un;
        w5[0] += un*e0; w5[1] += un*e1; w5[2] += un*e2; w5[3] += un*e3; w5[4] += un*e4;
      }
    }
    blockRed6(w5, sred);
    #pragma unroll
    for(int k=0;k<5;k++) v[k] = v[k] / (fmaxf(v[k]*w5[k], 1e-12f) * 5.f);
  }

  float bv5[5]; int bn5[5];
  #pragma unroll
  for(int k=0;k<5;k++){ bv5[k] = -1e30f; bn5[k] = 0x7FFFFFFF; }
  #pragma unroll
  for(int i=0;i<32;i++){
    const int n = tid + 512*i;
    float val[5] = {0.f,0.f,0.f,0.f,0.f};
    if (mb & (1u << i)){
      const float* lp = LGPTR(n);
      float lg[5];
      lg[0]=lp[0]; lg[1]=lp[256]; lg[2]=lp[512]; lg[3]=lp[768]; lg[4]=lp[1024];
      const float p0 = expf(lg[0]*20.f)*v[0];
      const float p1 = expf(lg[1]*20.f)*v[1];
      const float p2 = expf(lg[2]*20.f)*v[2];
      const float p3 = expf(lg[3]*20.f)*v[3];
      const float p4 = expf(lg[4]*20.f)*v[4];
      int bi = 0; float bb = p0;
      if (p1 > bb){ bb=p1; bi=1; }
      if (p2 > bb){ bb=p2; bi=2; }
      if (p3 > bb){ bb=p3; bi=3; }
      if (p4 > bb){ bb=p4; bi=4; }
      tgt[n] = (float)(bi + c5);
      const bool cc = (corr[n] > 0.5f);
      #pragma unroll
      for(int k=0;k<5;k++) val[k] = (cc && bi == k) ? lg[k] : 0.f;
    }
    #pragma unroll
    for(int k=0;k<5;k++){
      if (val[k] > bv5[k] || (val[k] == bv5[k] && n < bn5[k])){ bv5[k]=val[k]; bn5[k]=n; }
    }
  }
  #pragma unroll
  for(int k=0;k<5;k++){
    #pragma unroll
    for(int o=32;o>0;o>>=1){
      const float ov = __shfl_xor(bv5[k],o,64);
      const int   on = __shfl_xor(bn5[k],o,64);
      if (ov > bv5[k] || (ov == bv5[k] && on < bn5[k])){ bv5[k]=ov; bn5[k]=on; }
    }
  }
  const int wv = tid >> 6, lane = tid & 63;
  __syncthreads();
  if (lane == 0){
    #pragma unroll
    for(int k=0;k<5;k++){ srv[wv*5+k]=bv5[k]; srn[wv*5+k]=bn5[k]; }
  }
  __syncthreads();
  int topn[5];
  #pragma unroll
  for(int k=0;k<5;k++){
    float bb = srv[k]; int nn = srn[k];
    #pragma unroll
    for(int w2=1;w2<8;w2++){
      const float ov = srv[w2*5+k]; const int on = srn[w2*5+k];
      if (ov > bb || (ov == bb && on < nn)){ bb=ov; nn=on; }
    }
    topn[k] = nn;
  }
  __syncthreads();

  const bool hasp = (Bc > 0.f);
  #pragma unroll
  for(int k=0;k<5;k++){
    const int tn_ = topn[k];
    const float cf = corr[tn_];
    float pv = 0.f, proto = 0.f;
    if (tid < 256){
      pv    = patches[(size_t)tn_*DDIM + tid] * cf;
      proto = pnorm[(size_t)(c5+k)*DDIM + tid];
    }
    const float ss = blockSum512(pv*pv, sred);
    const float pnv = pv / fmaxf(sqrtf(ss), 1e-12f);
    const float pu = hasp ? (0.999f*proto + 0.001f*pnv) : proto;
    const float ss2 = blockSum512(tid<256 ? pu*pu : 0.f, sred);
    if (tid < 256) newp[(size_t)(c5+k)*DDIM + tid] = pu / fmaxf(sqrtf(ss2), 1e-12f);
  }
#undef LGPTR
}

extern "C" void kernel_launch(void* const* d_in, const int* in_sizes, int n_in,
                              void* d_out, int out_size, void* d_ws, size_t ws_size,
                              hipStream_t stream)
{
  const float* patch_tokens = (const float*)d_in[0];
  const float* proj_w       = (const float*)d_in[1];
  const float* proj_b       = (const float*)d_in[2];
  const float* ln_g         = (const float*)d_in[3];
  const float* ln_b         = (const float*)d_in[4];
  const float* prototypes   = (const float*)d_in[5];
  const int*   mask         = (const int*)d_in[6];
  float* out = (float*)d_out;
  float* ws  = (float*)d_ws;

  float*  patches = ws + W_PATCH;
  float*  pn      = ws + W_PN;
  float*  corr    = ws + W_CORR;
  float*  meanp   = ws + W_MEANP;
  ushort* pbf     = (ushort*)(ws + W_PBF);
  ushort* pnbf    = (ushort*)(ws + W_PNBF);

  float* pred = out;
  float* ppl  = out + O_PPL;
  float* img  = out + O_IMG;
  float* ct   = out + O_CONTR;
  float* tgt  = out + O_TGT;
  float* newp = out + O_NEWP;

  k_gemm1m<<<dim3(128,2),256,0,stream>>>(patch_tokens, proj_w, proj_b, patches);
  k_ln<<<4096,256,0,stream>>>(patches, ln_g, ln_b, pbf);
  k_pnorm<<<256,256,0,stream>>>(prototypes, pn, pnbf);
  k_gemm2m<<<dim3(128,8),256,0,stream>>>(pbf, pnbf, ct, ppl);
  k_pmean<<<64,256,0,stream>>>(patches, meanp);
  k_img2<<<252,256,0,stream>>>(meanp, pn, img);
  k_pred<<<51,256,0,stream>>>(img, pred);
  k_cls<<<4096,256,0,stream>>>(ct, mask, corr);
  k_sinkhorn<<<201,512,0,stream>>>(ppl, mask, corr, patches, pn, tgt, newp);
}

// Round 11
// 322.205 us; speedup vs baseline: 1.3989x; 1.1683x over previous
//
#include <hip/hip_runtime.h>
#include <hip/hip_bf16.h>

#define NROWS 16384
#define DBK   768
#define DDIM  256
#define NC    201
#define NK    5
#define NCK   1005

// output offsets (floats)
#define O_PPL    12864
#define O_IMG    16478784
#define O_CONTR  16543104
#define O_TGT    33009024
#define O_NEWP   33025408

// workspace offsets (floats)
#define W_PATCH  0u
#define W_PN     4194304u
#define W_CORR   4451584u
#define W_MEANP  4467968u
#define W_PBF    4484352u   // ushort region: 16384*256 bf16 patches
#define W_PNBF   8678656u   // ushort region: 1024*256 bf16 protos (zero-padded)
#define W_CNT    8809728u   // int[256]  per-class counts
#define W_FILLP  8809984u   // int[256]  fill cursors (memset together with CNT)
#define W_OFFS   8810240u   // int[256]  exclusive prefix
#define W_ROWS   8810496u   // int[16384] CSR row lists

typedef __attribute__((ext_vector_type(8))) short     short8;   // 8 bf16
typedef __attribute__((ext_vector_type(4))) float     f32x4;
typedef __attribute__((ext_vector_type(4))) unsigned int uint4v;
typedef __attribute__((ext_vector_type(4))) unsigned short ushort4v;

__device__ __forceinline__ float waveRedSum(float v){
  #pragma unroll
  for(int o=32;o>0;o>>=1) v += __shfl_xor(v,o,64);
  return v;
}

__device__ __forceinline__ unsigned short f2bf(float x){
  union { float f; unsigned u; } c; c.f = x;
  unsigned r = c.u + 0x7FFFu + ((c.u >> 16) & 1u);  // RNE
  return (unsigned short)(r >> 16);
}
__device__ __forceinline__ unsigned pack2(float a, float b){
  return (unsigned)f2bf(a) | ((unsigned)f2bf(b) << 16);
}
__device__ __forceinline__ uint4v pack8(float4 lo, float4 hi){
  uint4v u;
  u[0] = pack2(lo.x, lo.y); u[1] = pack2(lo.z, lo.w);
  u[2] = pack2(hi.x, hi.y); u[3] = pack2(hi.z, hi.w);
  return u;
}

// ============ GEMM1 (MFMA): out = patch_tokens @ proj_w^T + bias ============
__global__ __launch_bounds__(256,2) void k_gemm1m(
    const float* __restrict__ A, const float* __restrict__ W,
    const float* __restrict__ bias, float* __restrict__ out)
{
  __shared__ ushort As[4096];
  __shared__ ushort Bs[4096];
  const int tid = threadIdx.x;
  const int m0 = blockIdx.x * 128;
  const int n0 = blockIdx.y * 128;
  const int lane = tid & 63, wid = tid >> 6;
  const int wr = wid >> 1, wc = wid & 1;
  const int srow = tid >> 2, sslot = tid & 3;
  const int woff  = srow*32      + (sslot ^ ((srow>>1)&3))*8;
  const int woff2 = (srow+64)*32 + (sslot ^ ((srow>>1)&3))*8;
  const int l15 = lane & 15, kg = lane >> 4;
  const int rslot = (kg ^ ((l15>>1)&3))*8;
  f32x4 acc[4][4] = {};
  const float* Ap0 = A + (size_t)(m0+srow)*DBK + sslot*8;
  const float* Ap1 = Ap0 + (size_t)64*DBK;
  const float* Wp0 = W + (size_t)(n0+srow)*DBK + sslot*8;
  const float* Wp1 = Wp0 + (size_t)64*DBK;
  for (int k0 = 0; k0 < DBK; k0 += 32) {
    float4 a00 = *(const float4*)(Ap0+k0), a01 = *(const float4*)(Ap0+k0+4);
    float4 a10 = *(const float4*)(Ap1+k0), a11 = *(const float4*)(Ap1+k0+4);
    float4 b00 = *(const float4*)(Wp0+k0), b01 = *(const float4*)(Wp0+k0+4);
    float4 b10 = *(const float4*)(Wp1+k0), b11 = *(const float4*)(Wp1+k0+4);
    __syncthreads();
    *(uint4v*)&As[woff]  = pack8(a00, a01);
    *(uint4v*)&As[woff2] = pack8(a10, a11);
    *(uint4v*)&Bs[woff]  = pack8(b00, b01);
    *(uint4v*)&Bs[woff2] = pack8(b10, b11);
    __syncthreads();
    short8 af[4], bf[4];
    #pragma unroll
    for (int i=0;i<4;i++){
      af[i] = *(const short8*)&As[(wr*64 + i*16 + l15)*32 + rslot];
      bf[i] = *(const short8*)&Bs[(wc*64 + i*16 + l15)*32 + rslot];
    }
    #pragma unroll
    for (int i=0;i<4;i++)
      #pragma unroll
      for (int j=0;j<4;j++)
        acc[i][j] = __builtin_amdgcn_mfma_f32_16x16x32_bf16(af[i], bf[j], acc[i][j], 0,0,0);
  }
  #pragma unroll
  for (int j=0;j<4;j++){
    const int ncol = n0 + wc*64 + j*16 + l15;
    const float bv = bias[ncol];
    #pragma unroll
    for (int i=0;i<4;i++){
      const int mrow = m0 + wr*64 + i*16 + kg*4;
      #pragma unroll
      for (int r=0;r<4;r++)
        out[(size_t)(mrow+r)*DDIM + ncol] = acc[i][j][r] + bv;
    }
  }
}

// ============ GEMM2 (MFMA): logits = patches_bf16 @ pn_bf16^T, dual-layout store ============
__global__ __launch_bounds__(256,2) void k_gemm2m(
    const ushort* __restrict__ A, const ushort* __restrict__ B,
    float* __restrict__ ct, float* __restrict__ ppl)
{
  __shared__ ushort As[4096];
  __shared__ ushort Bs[4096];
  const int tid = threadIdx.x;
  const int m0 = blockIdx.x * 128;
  const int n0 = blockIdx.y * 128;
  const int lane = tid & 63, wid = tid >> 6;
  const int wr = wid >> 1, wc = wid & 1;
  const int srow = tid >> 2, sslot = tid & 3;
  const int woff  = srow*32      + (sslot ^ ((srow>>1)&3))*8;
  const int woff2 = (srow+64)*32 + (sslot ^ ((srow>>1)&3))*8;
  const int l15 = lane & 15, kg = lane >> 4;
  const int rslot = (kg ^ ((l15>>1)&3))*8;
  f32x4 acc[4][4] = {};
  const ushort* Ap0 = A + (size_t)(m0+srow)*DDIM + sslot*8;
  const ushort* Ap1 = Ap0 + (size_t)64*DDIM;
  const ushort* Bp0 = B + (size_t)(n0+srow)*DDIM + sslot*8;
  const ushort* Bp1 = Bp0 + (size_t)64*DDIM;
  for (int k0 = 0; k0 < DDIM; k0 += 32) {
    uint4v a0 = *(const uint4v*)(Ap0+k0);
    uint4v a1 = *(const uint4v*)(Ap1+k0);
    uint4v b0 = *(const uint4v*)(Bp0+k0);
    uint4v b1 = *(const uint4v*)(Bp1+k0);
    __syncthreads();
    *(uint4v*)&As[woff]  = a0;
    *(uint4v*)&As[woff2] = a1;
    *(uint4v*)&Bs[woff]  = b0;
    *(uint4v*)&Bs[woff2] = b1;
    __syncthreads();
    short8 af[4], bf[4];
    #pragma unroll
    for (int i=0;i<4;i++){
      af[i] = *(const short8*)&As[(wr*64 + i*16 + l15)*32 + rslot];
      bf[i] = *(const short8*)&Bs[(wc*64 + i*16 + l15)*32 + rslot];
    }
    #pragma unroll
    for (int i=0;i<4;i++)
      #pragma unroll
      for (int j=0;j<4;j++)
        acc[i][j] = __builtin_amdgcn_mfma_f32_16x16x32_bf16(af[i], bf[j], acc[i][j], 0,0,0);
  }
  const int bimg = m0 >> 8;
  #pragma unroll
  for (int i=0;i<4;i++){
    const int mrow = m0 + wr*64 + i*16 + kg*4;
    const int hw = mrow & 255;
    #pragma unroll
    for (int j=0;j<4;j++){
      const int ck = n0 + wc*64 + j*16 + l15;
      if (ck < NCK){
        #pragma unroll
        for (int r=0;r<4;r++)
          ct[(size_t)(mrow+r)*NCK + ck] = acc[i][j][r];
        *(f32x4*)&ppl[((size_t)(bimg*NCK+ck))*256 + hw] = acc[i][j];
      }
    }
  }
}

// ---------------- LayerNorm + L2n (in place) + bf16 copy ----------------
__global__ __launch_bounds__(256) void k_ln(float* __restrict__ p,
    const float* __restrict__ g, const float* __restrict__ bta, ushort* __restrict__ pbf)
{
  const int wid = threadIdx.x >> 6, lane = threadIdx.x & 63;
  const int row = blockIdx.x * 4 + wid;
  float4 x = *(float4*)&p[(size_t)row*DDIM + lane*4];
  float s = x.x + x.y + x.z + x.w;
  s = waveRedSum(s);
  const float mu = s * (1.f/256.f);
  const float d0=x.x-mu, d1=x.y-mu, d2=x.z-mu, d3=x.w-mu;
  float ss = d0*d0 + d1*d1 + d2*d2 + d3*d3;
  ss = waveRedSum(ss);
  const float var = ss * (1.f/256.f);
  const float rs = rsqrtf(var + 1e-5f);
  const float4 gv = *(const float4*)&g[lane*4];
  const float4 bv = *(const float4*)&bta[lane*4];
  const float y0 = d0*rs*gv.x + bv.x;
  const float y1 = d1*rs*gv.y + bv.y;
  const float y2 = d2*rs*gv.z + bv.z;
  const float y3 = d3*rs*gv.w + bv.w;
  float n2 = y0*y0 + y1*y1 + y2*y2 + y3*y3;
  n2 = waveRedSum(n2);
  const float inv = 1.f / fmaxf(sqrtf(n2), 1e-12f);
  float4 o; o.x=y0*inv; o.y=y1*inv; o.z=y2*inv; o.w=y3*inv;
  *(float4*)&p[(size_t)row*DDIM + lane*4] = o;
  ushort4v ob; ob[0]=f2bf(o.x); ob[1]=f2bf(o.y); ob[2]=f2bf(o.z); ob[3]=f2bf(o.w);
  *(ushort4v*)&pbf[(size_t)row*DDIM + lane*4] = ob;
}

// ---------------- prototype L2n -> fp32 + bf16 (rows 1005..1023 zeroed) ----------------
__global__ __launch_bounds__(256) void k_pnorm(const float* __restrict__ pr,
    float* __restrict__ out, ushort* __restrict__ obf)
{
  const int wid = threadIdx.x >> 6, lane = threadIdx.x & 63;
  const int row = blockIdx.x * 4 + wid;   // 0..1023
  if (row >= NCK){
    ushort4v z = {0,0,0,0};
    *(ushort4v*)&obf[(size_t)row*DDIM + lane*4] = z;
    return;
  }
  const float4 x = *(const float4*)&pr[(size_t)row*DDIM + lane*4];
  float n2 = x.x*x.x + x.y*x.y + x.z*x.z + x.w*x.w;
  n2 = waveRedSum(n2);
  const float inv = 1.f / fmaxf(sqrtf(n2), 1e-12f);
  float4 o; o.x=x.x*inv; o.y=x.y*inv; o.z=x.z*inv; o.w=x.w*inv;
  *(float4*)&out[(size_t)row*DDIM + lane*4] = o;
  ushort4v ob; ob[0]=f2bf(o.x); ob[1]=f2bf(o.y); ob[2]=f2bf(o.z); ob[3]=f2bf(o.w);
  *(ushort4v*)&obf[(size_t)row*DDIM + lane*4] = ob;
}

// ---------------- mean patch per image (fp32, exact-linear img path) ----------------
__global__ __launch_bounds__(256) void k_pmean(const float* __restrict__ p, float* __restrict__ mp)
{
  const int b = blockIdx.x, d = threadIdx.x;
  const float* base = p + (size_t)b*256*DDIM + d;
  float s = 0.f;
  #pragma unroll 8
  for (int r=0;r<256;r++) s += base[(size_t)r*DDIM];
  mp[b*DDIM + d] = s * (1.f/256.f);
}

// ---------------- img_logits = mean_patch . proto (fp32 dot-256) ----------------
__global__ __launch_bounds__(256) void k_img2(const float* __restrict__ mp,
    const float* __restrict__ pn, float* __restrict__ img)
{
  const int gid = blockIdx.x*256 + threadIdx.x;
  if (gid >= 64*NCK) return;
  const int b = gid / NCK, ck = gid - b*NCK;
  const float4* a = (const float4*)&mp[b*DDIM];
  const float4* q = (const float4*)&pn[(size_t)ck*DDIM];
  float s = 0.f;
  #pragma unroll 8
  for (int d=0; d<64; d++){
    const float4 x = a[d], y = q[d];
    s += x.x*y.x + x.y*y.y + x.z*y.z + x.w*y.w;
  }
  img[gid] = s;
}

// ---------------- pred_logits: sum over k ----------------
__global__ __launch_bounds__(256) void k_pred(const float* __restrict__ img, float* __restrict__ pred)
{
  const int gid = blockIdx.x*256 + threadIdx.x;
  if (gid >= 64*NC) return;
  const int b = gid / NC, c = gid % NC;
  const float* ip = &img[(size_t)b*NCK + c*5];
  pred[(size_t)b*NC + c] = ip[0]+ip[1]+ip[2]+ip[3]+ip[4];
}

// ---------------- class_preds -> correct_f (wave per row) ----------------
__global__ __launch_bounds__(256) void k_cls(const float* __restrict__ ct,
    const int* __restrict__ mask, float* __restrict__ corr)
{
  const int wid = threadIdx.x >> 6, lane = threadIdx.x & 63;
  const int n = blockIdx.x * 4 + wid;
  const float* row = &ct[(size_t)n*NCK];
  float bv = -1e30f; int bc = 0x7FFFFFFF;
  #pragma unroll
  for(int j=0;j<16;j++){
    const int ck = lane + 64*j;
    if (ck < NCK){
      const float v = row[ck];
      const int c = ck / 5;
      if (v > bv || (v == bv && c < bc)){ bv = v; bc = c; }
    }
  }
  #pragma unroll
  for(int o=32;o>0;o>>=1){
    const float ov = __shfl_xor(bv,o,64);
    const int   oc = __shfl_xor(bc,o,64);
    if (ov > bv || (ov == bv && oc < bc)){ bv = ov; bc = oc; }
  }
  if (lane == 0) corr[n] = (mask[n] == bc) ? 1.f : 0.f;
}

// ---------------- class compaction: hist / scan / fill ----------------
__global__ __launch_bounds__(256) void k_hist(const int* __restrict__ mask, int* __restrict__ cnt)
{
  const int n = blockIdx.x*256 + threadIdx.x;
  atomicAdd(&cnt[mask[n]], 1);
}

__global__ __launch_bounds__(256) void k_scan(const int* __restrict__ cnt, int* __restrict__ offs)
{
  __shared__ int sc[256];
  const int tid = threadIdx.x;
  const int v = (tid < NC) ? cnt[tid] : 0;
  sc[tid] = v;
  __syncthreads();
  #pragma unroll
  for (int s=1; s<256; s<<=1){
    const int add = (tid >= s) ? sc[tid-s] : 0;
    __syncthreads();
    sc[tid] += add;
    __syncthreads();
  }
  offs[tid] = sc[tid] - v;   // exclusive prefix
}

__global__ __launch_bounds__(256) void k_fill(const int* __restrict__ mask,
    const int* __restrict__ offs, int* __restrict__ fillp, int* __restrict__ rows)
{
  const int n = blockIdx.x*256 + threadIdx.x;
  const int c = mask[n];
  const int pos = atomicAdd(&fillp[c], 1);
  rows[offs[c] + pos] = n;
}

// ---------------- Sinkhorn v2: one row per thread, logits in registers ----------------
__device__ __forceinline__ void blockRed5_256(float* a, float* ls){
  #pragma unroll
  for (int j=0;j<5;j++) a[j] = waveRedSum(a[j]);
  const int wv = threadIdx.x >> 6, lane = threadIdx.x & 63;
  __syncthreads();
  if (lane == 0){
    #pragma unroll
    for (int j=0;j<5;j++) ls[wv*5+j] = a[j];
  }
  __syncthreads();
  #pragma unroll
  for (int j=0;j<5;j++) a[j] = ls[j] + ls[5+j] + ls[10+j] + ls[15+j];
}

__device__ __forceinline__ float blockSum256(float x, float* ls4){
  x = waveRedSum(x);
  const int wv = threadIdx.x >> 6, lane = threadIdx.x & 63;
  __syncthreads();
  if (lane == 0) ls4[wv] = x;
  __syncthreads();
  return ls4[0] + ls4[1] + ls4[2] + ls4[3];
}

__global__ __launch_bounds__(256,4) void k_sink2(
    const float* __restrict__ ppl, const int* __restrict__ cnt,
    const int* __restrict__ offs, const int* __restrict__ rows,
    const float* __restrict__ corr, const float* __restrict__ patches,
    const float* __restrict__ pn, float* __restrict__ tgt, float* __restrict__ newp)
{
  const int c = blockIdx.x, c5 = c*5, tid = threadIdx.x;
  const int wv = tid >> 6, lane = tid & 63;
  __shared__ float ls[20];
  __shared__ float lsv[20];
  __shared__ int   lsn[20];
  const int nr  = cnt[c];
  const int off = offs[c];
  const bool act = tid < nr;
  int n = 0; float lg[5], e[5]; float cf = 0.f;
  if (act){
    n = rows[off + tid];
    const float* lp = ppl + ((size_t)((n>>8)*NCK) + c5)*256 + (n&255);
    #pragma unroll
    for (int k=0;k<5;k++){ lg[k] = lp[k*256]; e[k] = expf(lg[k]*20.f); }
    cf = corr[n];
  } else {
    #pragma unroll
    for (int k=0;k<5;k++){ lg[k] = 0.f; e[k] = 0.f; }
  }
  // column sums of E over masked rows
  float a[5];
  #pragma unroll
  for (int k=0;k<5;k++) a[k] = e[k];
  blockRed5_256(a, ls);
  const float Bcc = (float)(nr > 0 ? nr : 1);
  const float S = a[0]+a[1]+a[2]+a[3]+a[4];
  const float v0 = 1.f / fmaxf(S, 1e-12f);
  float v[5];
  #pragma unroll
  for (int k=0;k<5;k++) v[k] = v0 / (fmaxf(v0*a[k], 1e-12f) * 5.f);
  // 2 fused (row step t, col step t+1) updates
  float u = 1.f;
  #pragma unroll 1
  for (int t=0;t<2;t++){
    float w[5] = {0.f,0.f,0.f,0.f,0.f};
    if (act){
      const float s = e[0]*v[0] + e[1]*v[1] + e[2]*v[2] + e[3]*v[3] + e[4]*v[4];
      const float un = u / fmaxf(u*s, 1e-12f) / Bcc;
      u = un;
      #pragma unroll
      for (int k=0;k<5;k++) w[k] = un * e[k];
    }
    blockRed5_256(w, ls);
    #pragma unroll
    for (int k=0;k<5;k++) v[k] = v[k] / (fmaxf(v[k]*w[k], 1e-12f) * 5.f);
  }
  // per-row argmax -> tgt; score candidates
  int bi = 0;
  if (act){
    float bb = e[0]*v[0];
    #pragma unroll
    for (int k=1;k<5;k++){
      const float p = e[k]*v[k];
      if (p > bb){ bb = p; bi = k; }
    }
    tgt[n] = (float)(bi + c5);
  }
  const bool cc = act && (cf > 0.5f);
  float sv[5]; int sn[5];
  #pragma unroll
  for (int k=0;k<5;k++){
    float rv = (cc && bi == k) ? lg[k] : 0.f;
    int   rn = act ? n : 0x7FFFFFFF;
    // zero-score candidate at index tid (covers JAX argmax-of-zeros semantics)
    if (0.f > rv || (0.f == rv && tid < rn)){ rv = 0.f; rn = tid; }
    sv[k] = rv; sn[k] = rn;
  }
  #pragma unroll
  for (int k=0;k<5;k++){
    #pragma unroll
    for (int o=32;o>0;o>>=1){
      const float ov = __shfl_xor(sv[k],o,64);
      const int   on = __shfl_xor(sn[k],o,64);
      if (ov > sv[k] || (ov == sv[k] && on < sn[k])){ sv[k]=ov; sn[k]=on; }
    }
  }
  __syncthreads();
  if (lane == 0){
    #pragma unroll
    for (int k=0;k<5;k++){ lsv[wv*5+k] = sv[k]; lsn[wv*5+k] = sn[k]; }
  }
  __syncthreads();
  int topn[5];
  #pragma unroll
  for (int k=0;k<5;k++){
    float bb = lsv[k]; int nn = lsn[k];
    #pragma unroll
    for (int w2=1;w2<4;w2++){
      const float ov = lsv[w2*5+k]; const int on = lsn[w2*5+k];
      if (ov > bb || (ov == bb && on < nn)){ bb = ov; nn = on; }
    }
    topn[k] = nn;
  }
  // prototype update
  const bool hasp = (nr > 0);
  #pragma unroll 1
  for (int k=0;k<5;k++){
    const int tn_ = topn[k];
    const float cfa = corr[tn_];
    const float pv = patches[(size_t)tn_*DDIM + tid] * cfa;
    const float proto = pn[(size_t)(c5+k)*DDIM + tid];
    const float ss = blockSum256(pv*pv, ls);
    const float pnv = pv / fmaxf(sqrtf(ss), 1e-12f);
    const float pu = hasp ? (0.999f*proto + 0.001f*pnv) : proto;
    const float ss2 = blockSum256(pu*pu, ls);
    newp[(size_t)(c5+k)*DDIM + tid] = pu / fmaxf(sqrtf(ss2), 1e-12f);
  }
}

extern "C" void kernel_launch(void* const* d_in, const int* in_sizes, int n_in,
                              void* d_out, int out_size, void* d_ws, size_t ws_size,
                              hipStream_t stream)
{
  const float* patch_tokens = (const float*)d_in[0];
  const float* proj_w       = (const float*)d_in[1];
  const float* proj_b       = (const float*)d_in[2];
  const float* ln_g         = (const float*)d_in[3];
  const float* ln_b         = (const float*)d_in[4];
  const float* prototypes   = (const float*)d_in[5];
  const int*   mask         = (const int*)d_in[6];
  float* out = (float*)d_out;
  float* ws  = (float*)d_ws;

  float*  patches = ws + W_PATCH;
  float*  pn      = ws + W_PN;
  float*  corr    = ws + W_CORR;
  float*  meanp   = ws + W_MEANP;
  ushort* pbf     = (ushort*)(ws + W_PBF);
  ushort* pnbf    = (ushort*)(ws + W_PNBF);
  int*    cnt     = (int*)(ws + W_CNT);
  int*    fillp   = (int*)(ws + W_FILLP);
  int*    offs    = (int*)(ws + W_OFFS);
  int*    rows    = (int*)(ws + W_ROWS);

  float* pred = out;
  float* ppl  = out + O_PPL;
  float* img  = out + O_IMG;
  float* ct   = out + O_CONTR;
  float* tgt  = out + O_TGT;
  float* newp = out + O_NEWP;

  // class compaction (needs only mask) — cnt+fillp zeroed in one memset
  hipMemsetAsync((void*)cnt, 0, 512*sizeof(int), stream);
  k_hist<<<64,256,0,stream>>>(mask, cnt);
  k_scan<<<1,256,0,stream>>>(cnt, offs);
  k_fill<<<64,256,0,stream>>>(mask, offs, fillp, rows);

  k_gemm1m<<<dim3(128,2),256,0,stream>>>(patch_tokens, proj_w, proj_b, patches);
  k_ln<<<4096,256,0,stream>>>(patches, ln_g, ln_b, pbf);
  k_pnorm<<<256,256,0,stream>>>(prototypes, pn, pnbf);
  k_gemm2m<<<dim3(128,8),256,0,stream>>>(pbf, pnbf, ct, ppl);
  k_pmean<<<64,256,0,stream>>>(patches, meanp);
  k_img2<<<252,256,0,stream>>>(meanp, pn, img);
  k_pred<<<51,256,0,stream>>>(img, pred);
  k_cls<<<4096,256,0,stream>>>(ct, mask, corr);
  k_sink2<<<201,256,0,stream>>>(ppl, cnt, offs, rows, corr, patches, pn, tgt, newp);
}